// Round 2
// baseline (1741.490 us; speedup 1.0000x reference)
//
#include <hip/hip_runtime.h>
#include <cfloat>

#define B_TOTAL 131072
#define N_CB    1024
#define DIM     64
#define DEPTH   4
#define BM      64      // rows per block
#define NT      128     // codebook cols per LDS tile
#define NTILES  (N_CB / NT)
#define EPS     0.015625f   // candidate band; ~15x fp32 dist error bound

// Exact fp64 distance for candidate cidx. rd0/rd1 are this lane's 2 residual
// dims (lane tc owns dims 2tc,2tc+1 of each of its group's rows); reduce over
// the 32 lanes of the row-group (xor masks <=16 stay within the wave half).
__device__ __forceinline__ double refine_dist(const float* __restrict__ cb,
                                              int cidx, int tc,
                                              double rd0, double rd1, double z2) {
  const float2 cf = *(const float2*)(cb + (size_t)cidx * DIM + 2 * tc);
  const double c0 = (double)cf.x, c1 = (double)cf.y;
  double dot = rd0 * c0 + rd1 * c1;
  double cc  = c0 * c0 + c1 * c1;
  #pragma unroll
  for (int m = 1; m < 32; m <<= 1) {
    dot += __shfl_xor(dot, m);
    cc  += __shfl_xor(cc, m);
  }
  return z2 + cc - 2.0 * dot;
}

// LDS: cbT 32KB + resT 16KB + c2s 4KB = 52KB -> up to 3 blocks/CU
__global__ __launch_bounds__(256, 2)
void rvq_kernel(const float* __restrict__ z,
                const float* __restrict__ cb,
                float* __restrict__ out) {
  __shared__ __align__(16) float cbT[DIM][NT];   // [k][n] transposed codebook tile
  __shared__ __align__(16) float resT[DIM][BM];  // [k][row] fp32 residual (cast of fp64)
  __shared__ __align__(16) float c2s[N_CB];

  const int tid  = threadIdx.x;
  const int tc   = tid & 31;   // column lane within row-group
  const int tr   = tid >> 5;   // row-group id (8 groups x 8 rows)
  const int row0 = blockIdx.x * BM;

  float* zq   = out;                              // [B_TOTAL][DIM]
  float* maps = out + (size_t)B_TOTAL * DIM;      // [DEPTH][B_TOTAL][N_CB]

  // ---- codebook squared norms (fp32; only feeds map values + coarse band) ----
  for (int r = tid; r < N_CB; r += 256) {
    const float4* p = (const float4*)(cb + (size_t)r * DIM);
    float s = 0.f;
    #pragma unroll
    for (int i = 0; i < DIM / 4; ++i) {
      float4 v = p[i];
      s += v.x * v.x; s += v.y * v.y; s += v.z * v.z; s += v.w * v.w;
    }
    c2s[r] = s;
  }

  // ---- init fp64 residual (2 dims/lane, 8 rows/lane) + fp32 LDS copy ----
  double rd[8][2];
  #pragma unroll
  for (int i = 0; i < 8; ++i) {
    const int row = tr * 8 + i;
    const float2 v = *(const float2*)(z + (size_t)(row0 + row) * DIM + 2 * tc);
    rd[i][0] = (double)v.x;
    rd[i][1] = (double)v.y;
    resT[2 * tc + 0][row] = v.x;
    resT[2 * tc + 1][row] = v.y;
  }
  __syncthreads();

  for (int depth = 0; depth < DEPTH; ++depth) {
    // ---- exact fp64 row norms (shuffle-reduced; all lanes hold result) ----
    double z264[8];
    #pragma unroll
    for (int i = 0; i < 8; ++i) {
      double p = rd[i][0] * rd[i][0] + rd[i][1] * rd[i][1];
      #pragma unroll
      for (int m = 1; m < 32; m <<= 1) p += __shfl_xor(p, m);
      z264[i] = p;
    }

    float m1[8], m2[8]; int i1[8], i2[8];
    #pragma unroll
    for (int i = 0; i < 8; ++i) { m1[i] = FLT_MAX; m2[i] = FLT_MAX; i1[i] = 0; i2[i] = 0; }

    for (int tile = 0; tile < NTILES; ++tile) {
      // ---- stage codebook tile transposed (conflict-free: n = lane) ----
      {
        const int n  = tid & (NT - 1);
        const int kh = (tid >> 7) * 32;
        const float4* p = (const float4*)(cb + (size_t)(tile * NT + n) * DIM + kh);
        #pragma unroll
        for (int i = 0; i < 8; ++i) {
          float4 v = p[i];
          cbT[kh + i * 4 + 0][n] = v.x;
          cbT[kh + i * 4 + 1][n] = v.y;
          cbT[kh + i * 4 + 2][n] = v.z;
          cbT[kh + i * 4 + 3][n] = v.w;
        }
      }
      __syncthreads();

      float acc[8][4];
      #pragma unroll
      for (int i = 0; i < 8; ++i)
        #pragma unroll
        for (int j = 0; j < 4; ++j) acc[i][j] = 0.f;

      #pragma unroll 16
      for (int k = 0; k < DIM; ++k) {
        float4 b  = *(const float4*)&cbT[k][tc * 4];
        float4 a0 = *(const float4*)&resT[k][tr * 8];
        float4 a1 = *(const float4*)&resT[k][tr * 8 + 4];
        acc[0][0] += a0.x * b.x; acc[0][1] += a0.x * b.y; acc[0][2] += a0.x * b.z; acc[0][3] += a0.x * b.w;
        acc[1][0] += a0.y * b.x; acc[1][1] += a0.y * b.y; acc[1][2] += a0.y * b.z; acc[1][3] += a0.y * b.w;
        acc[2][0] += a0.z * b.x; acc[2][1] += a0.z * b.y; acc[2][2] += a0.z * b.z; acc[2][3] += a0.z * b.w;
        acc[3][0] += a0.w * b.x; acc[3][1] += a0.w * b.y; acc[3][2] += a0.w * b.z; acc[3][3] += a0.w * b.w;
        acc[4][0] += a1.x * b.x; acc[4][1] += a1.x * b.y; acc[4][2] += a1.x * b.z; acc[4][3] += a1.x * b.w;
        acc[5][0] += a1.y * b.x; acc[5][1] += a1.y * b.y; acc[5][2] += a1.y * b.z; acc[5][3] += a1.y * b.w;
        acc[6][0] += a1.z * b.x; acc[6][1] += a1.z * b.y; acc[6][2] += a1.z * b.z; acc[6][3] += a1.z * b.w;
        acc[7][0] += a1.w * b.x; acc[7][1] += a1.w * b.y; acc[7][2] += a1.w * b.z; acc[7][3] += a1.w * b.w;
      }

      // ---- epilogue: dist, map store, per-lane top-2 tracking ----
      const int cbase = tile * NT + tc * 4;
      const float c0 = c2s[cbase + 0], c1 = c2s[cbase + 1],
                  c2v = c2s[cbase + 2], c3 = c2s[cbase + 3];
      #pragma unroll
      for (int i = 0; i < 8; ++i) {
        const int row = tr * 8 + i;
        const float zz = (float)z264[i];
        float4 dv;
        dv.x = (zz + c0)  - 2.f * acc[i][0];
        dv.y = (zz + c1)  - 2.f * acc[i][1];
        dv.z = (zz + c2v) - 2.f * acc[i][2];
        dv.w = (zz + c3)  - 2.f * acc[i][3];
        // ascending index order; strict < keeps first occurrence
        if (dv.x < m1[i]) { m2[i] = m1[i]; i2[i] = i1[i]; m1[i] = dv.x; i1[i] = cbase + 0; }
        else if (dv.x < m2[i]) { m2[i] = dv.x; i2[i] = cbase + 0; }
        if (dv.y < m1[i]) { m2[i] = m1[i]; i2[i] = i1[i]; m1[i] = dv.y; i1[i] = cbase + 1; }
        else if (dv.y < m2[i]) { m2[i] = dv.y; i2[i] = cbase + 1; }
        if (dv.z < m1[i]) { m2[i] = m1[i]; i2[i] = i1[i]; m1[i] = dv.z; i1[i] = cbase + 2; }
        else if (dv.z < m2[i]) { m2[i] = dv.z; i2[i] = cbase + 2; }
        if (dv.w < m1[i]) { m2[i] = m1[i]; i2[i] = i1[i]; m1[i] = dv.w; i1[i] = cbase + 3; }
        else if (dv.w < m2[i]) { m2[i] = dv.w; i2[i] = cbase + 3; }
        *(float4*)&maps[((size_t)depth * B_TOTAL + row0 + row) * N_CB + cbase] = dv;
      }
      __syncthreads();  // before next tile overwrites cbT
    }

    // ---- per-row decision (fp32 coarse, fp64 exact when candidates tie) ----
    #pragma unroll
    for (int i = 0; i < 8; ++i) {
      float v = m1[i]; int ix = i1[i];
      #pragma unroll
      for (int m = 1; m < 32; m <<= 1) {
        float ov = __shfl_xor(v, m);
        int   oi = __shfl_xor(ix, m);
        if (ov < v || (ov == v && oi < ix)) { v = ov; ix = oi; }
      }
      const float thr = v + EPS;
      const unsigned long long b1a = __ballot(m1[i] <= thr);
      const unsigned long long b2a = __ballot(m2[i] <= thr);
      const unsigned sh = tid & 32;           // select this wave-half's 32 bits
      unsigned b1 = (unsigned)(b1a >> sh);
      unsigned b2 = (unsigned)(b2a >> sh);
      int pred = ix;
      if (__popc(b1) + __popc(b2) > 1) {
        double best = DBL_MAX; int bix = 0x7fffffff;
        unsigned rem = b1;
        while (rem) {
          const int l = __ffs(rem) - 1; rem &= rem - 1;
          const int cidx = __shfl(i1[i], l, 32);
          const double d = refine_dist(cb, cidx, tc, rd[i][0], rd[i][1], z264[i]);
          if (d < best || (d == best && cidx < bix)) { best = d; bix = cidx; }
        }
        rem = b2;
        while (rem) {
          const int l = __ffs(rem) - 1; rem &= rem - 1;
          const int cidx = __shfl(i2[i], l, 32);
          const double d = refine_dist(cb, cidx, tc, rd[i][0], rd[i][1], z264[i]);
          if (d < best || (d == best && cidx < bix)) { best = d; bix = cidx; }
        }
        pred = bix;
      }
      // ---- residual update (fp64-exact) + refresh fp32 LDS copy ----
      const float2 cf = *(const float2*)(cb + (size_t)pred * DIM + 2 * tc);
      rd[i][0] -= (double)cf.x;
      rd[i][1] -= (double)cf.y;
      const int row = tr * 8 + i;
      resT[2 * tc + 0][row] = (float)rd[i][0];
      resT[2 * tc + 1][row] = (float)rd[i][1];
    }
    __syncthreads();
  }

  // ---- z_q = z - residual_final (fp64 then cast) ----
  #pragma unroll
  for (int i = 0; i < 8; ++i) {
    const size_t grow = (size_t)(row0 + tr * 8 + i);
    const float2 v = *(const float2*)(z + grow * DIM + 2 * tc);
    float2 o;
    o.x = (float)((double)v.x - rd[i][0]);
    o.y = (float)((double)v.y - rd[i][1]);
    *(float2*)(zq + grow * DIM + 2 * tc) = o;
  }
}

extern "C" void kernel_launch(void* const* d_in, const int* in_sizes, int n_in,
                              void* d_out, int out_size, void* d_ws, size_t ws_size,
                              hipStream_t stream) {
  const float* z  = (const float*)d_in[0];
  const float* cb = (const float*)d_in[1];
  float* out = (float*)d_out;
  dim3 grid(B_TOTAL / BM);
  dim3 block(256);
  hipLaunchKernelGGL(rvq_kernel, grid, block, 0, stream, z, cb, out);
}

// Round 3
// 963.770 us; speedup vs baseline: 1.8070x; 1.8070x over previous
//
#include <hip/hip_runtime.h>
#include <cfloat>

#define B_TOTAL 131072
#define N_CB    1024
#define DIM     64
#define DEPTH   4
#define BM      128     // rows per block (4 waves x 32)
#define RS      68      // res row stride (floats): 272B = 17x16B, 16B-aligned rows
#define EPS     0.0156f

typedef __bf16 bf16x8 __attribute__((ext_vector_type(8)));
typedef unsigned short u16x8 __attribute__((ext_vector_type(8)));
typedef float f32x16 __attribute__((ext_vector_type(16)));

#define MFMA(a, b, c) __builtin_amdgcn_mfma_f32_32x32x16_bf16(a, b, c, 0, 0, 0)

static __device__ __forceinline__ unsigned short f2bf(float f) {
  unsigned u = __builtin_bit_cast(unsigned, f);
  return (unsigned short)((u + 0x7fffu + ((u >> 16) & 1u)) >> 16);
}
static __device__ __forceinline__ float bf2f(unsigned short h) {
  unsigned u = ((unsigned)h) << 16;
  return __builtin_bit_cast(float, u);
}

// Pre-split codebook into MFMA B-fragment layout (bh/bl) + fp32 norms.
// frag element: [(t*4+m)*64 + lane][j] = cb[32t + (lane&31)][16m + 8*(lane>>5) + j]
__global__ void prep_kernel(const float* __restrict__ cb,
                            unsigned short* __restrict__ bh,
                            unsigned short* __restrict__ bl,
                            float* __restrict__ c2) {
  const int t = blockIdx.x;            // 0..31
  const int l = threadIdx.x;           // 0..63
  const int tc = l & 31, hi = l >> 5;
  const int row = 32 * t + tc;
  #pragma unroll
  for (int m = 0; m < 4; ++m) {
    const float* p = cb + row * DIM + 16 * m + 8 * hi;
    const size_t o = (((size_t)t * 4 + m) * 64 + l) * 8;
    #pragma unroll
    for (int j = 0; j < 8; ++j) {
      float f = p[j];
      unsigned short h = f2bf(f);
      bh[o + j] = h;
      bl[o + j] = f2bf(f - bf2f(h));
    }
  }
  if (hi == 0) {
    const float* p = cb + row * DIM;
    float s = 0.f;
    #pragma unroll
    for (int k = 0; k < DIM; ++k) s += p[k] * p[k];
    c2[row] = s;
  }
}

// LDS: res 34816 + c2s 4096 + z2s 512 + preds 512 = ~40KB -> 2 blocks/CU at VGPR cap
__global__ __launch_bounds__(256, 2)
void rvq_mfma_kernel(const float* __restrict__ z,
                     const float* __restrict__ cbg,
                     const unsigned short* __restrict__ bh,
                     const unsigned short* __restrict__ bl,
                     const float* __restrict__ c2g,
                     float* __restrict__ out) {
  __shared__ __align__(16) float res[BM][RS];  // fp32 residual, per-wave 32-row panels
  __shared__ float c2s[N_CB];
  __shared__ float z2s[BM];
  __shared__ int   preds[BM];

  const int tid  = threadIdx.x;
  const int wave = tid >> 6;
  const int l    = tid & 63;
  const int tc   = l & 31;
  const int hi   = l >> 5;
  const int wr   = wave * 32;
  const int row0 = blockIdx.x * BM;

  float* zq   = out;
  float* maps = out + (size_t)B_TOTAL * DIM;

  // ---- stage z -> res (coalesced), c2 -> LDS ----
  {
    const float4* z4 = (const float4*)(z + (size_t)row0 * DIM);
    #pragma unroll
    for (int i = 0; i < 8; ++i) {
      const int f = i * 256 + tid;
      float4 v = z4[f];
      const int r = (f * 4) >> 6, d0 = (f * 4) & 63;
      *(float4*)&res[r][d0] = v;
    }
    for (int i = tid; i < N_CB; i += 256) c2s[i] = c2g[i];
  }
  __syncthreads();

  for (int depth = 0; depth < DEPTH; ++depth) {
    // ---- A fragments (split bf16) + fp32 row norm ----
    bf16x8 Ah[4], Al[4];
    float zp = 0.f;
    {
      const int arow = wr + tc;
      #pragma unroll
      for (int m = 0; m < 4; ++m) {
        u16x8 uh, ul;
        #pragma unroll
        for (int jj = 0; jj < 8; ++jj) {
          const float f = res[arow][16 * m + 8 * hi + jj];
          zp += f * f;
          const unsigned short h = f2bf(f);
          uh[jj] = h;
          ul[jj] = f2bf(f - bf2f(h));
        }
        Ah[m] = __builtin_bit_cast(bf16x8, uh);
        Al[m] = __builtin_bit_cast(bf16x8, ul);
      }
    }
    zp += __shfl_xor(zp, 32);          // partner lane holds the other 32 dims
    if (l < 32) z2s[wr + l] = zp;

    float z2v[16];
    #pragma unroll
    for (int s = 0; s < 16; ++s)
      z2v[s] = z2s[wr + (s & 3) + 8 * (s >> 2) + 4 * hi];

    float m1[16], m2[16];
    unsigned ip[16];                   // (i1 << 16) | i2
    #pragma unroll
    for (int s = 0; s < 16; ++s) { m1[s] = FLT_MAX; m2[s] = FLT_MAX; ip[s] = 0; }

    float* mbase = maps + ((size_t)depth * B_TOTAL + row0 + wr + 4 * hi) * N_CB + tc;

    for (int t = 0; t < 32; ++t) {
      const bf16x8* bhp = (const bf16x8*)bh + (size_t)(t * 4) * 64 + l;
      const bf16x8* blp = (const bf16x8*)bl + (size_t)(t * 4) * 64 + l;
      const bf16x8 Bh0 = bhp[0], Bh1 = bhp[64], Bh2 = bhp[128], Bh3 = bhp[192];
      const bf16x8 Bl0 = blp[0], Bl1 = blp[64], Bl2 = blp[128], Bl3 = blp[192];

      f32x16 acc;
      #pragma unroll
      for (int s = 0; s < 16; ++s) acc[s] = 0.f;
      acc = MFMA(Ah[0], Bh0, acc);
      acc = MFMA(Ah[1], Bh1, acc);
      acc = MFMA(Ah[2], Bh2, acc);
      acc = MFMA(Ah[3], Bh3, acc);
      acc = MFMA(Ah[0], Bl0, acc);
      acc = MFMA(Ah[1], Bl1, acc);
      acc = MFMA(Ah[2], Bl2, acc);
      acc = MFMA(Ah[3], Bl3, acc);
      acc = MFMA(Al[0], Bh0, acc);
      acc = MFMA(Al[1], Bh1, acc);
      acc = MFMA(Al[2], Bh2, acc);
      acc = MFMA(Al[3], Bh3, acc);

      const float c2v = c2s[32 * t + tc];
      const unsigned col = 32 * t + tc;
      float* mp = mbase + 32 * t;
      #pragma unroll
      for (int s = 0; s < 16; ++s) {
        const float d = (z2v[s] + c2v) - 2.f * acc[s];
        mp[((s & 3) + 8 * (s >> 2)) * N_CB] = d;   // 2x128B segments per wave store
        if (d < m1[s])      { m2[s] = m1[s]; ip[s] = (col << 16) | (ip[s] >> 16); m1[s] = d; }
        else if (d < m2[s]) { m2[s] = d;     ip[s] = (ip[s] & 0xffff0000u) | col; }
      }
    }

    // ---- cross-lane top-2 merge over the 32 lanes sharing each row ----
    #pragma unroll
    for (int s = 0; s < 16; ++s) {
      #pragma unroll
      for (int msk = 1; msk < 32; msk <<= 1) {
        const float    om1 = __shfl_xor(m1[s], msk);
        const float    om2 = __shfl_xor(m2[s], msk);
        const unsigned oip = (unsigned)__shfl_xor((int)ip[s], msk);
        const unsigned i1 = ip[s] >> 16, i2 = ip[s] & 0xffffu;
        const unsigned oi1 = oip >> 16,  oi2 = oip & 0xffffu;
        const bool obet = (om1 < m1[s]) || (om1 == m1[s] && oi1 < i1);
        const float    f1 = obet ? om1 : m1[s];
        const unsigned fi = obet ? oi1 : i1;
        const float    lm = obet ? m1[s] : om1;
        const unsigned li = obet ? i1 : oi1;
        float s2 = m2[s]; unsigned si = i2;
        if (om2 < s2 || (om2 == s2 && oi2 < si)) { s2 = om2; si = oi2; }
        if (lm  < s2 || (lm  == s2 && li  < si)) { s2 = lm;  si = li;  }
        m1[s] = f1; m2[s] = s2; ip[s] = (fi << 16) | si;
      }
    }

    // ---- decide pred per row; fp64 exact refine when band is ambiguous ----
    #pragma unroll
    for (int s = 0; s < 16; ++s) {
      const int row = wr + (s & 3) + 8 * (s >> 2) + 4 * hi;
      int pred = (int)(ip[s] >> 16);
      if (m2[s] <= m1[s] + EPS) {      // uniform within the 32-lane half
        const int ca = (int)(ip[s] >> 16), cb2 = (int)(ip[s] & 0xffffu);
        const float2 rv  = *(const float2*)&res[row][2 * tc];
        const float2 cva = *(const float2*)(cbg + (size_t)ca  * DIM + 2 * tc);
        const float2 cvb = *(const float2*)(cbg + (size_t)cb2 * DIM + 2 * tc);
        double da = ((double)rv.x - cva.x) * ((double)rv.x - cva.x)
                  + ((double)rv.y - cva.y) * ((double)rv.y - cva.y);
        double db = ((double)rv.x - cvb.x) * ((double)rv.x - cvb.x)
                  + ((double)rv.y - cvb.y) * ((double)rv.y - cvb.y);
        #pragma unroll
        for (int msk = 1; msk < 32; msk <<= 1) {
          da += __shfl_xor(da, msk);
          db += __shfl_xor(db, msk);
        }
        if (db < da || (db == da && cb2 < ca)) pred = cb2;
      }
      if (tc == 0) preds[row] = pred;
    }

    // ---- residual -= codebook[pred] (fp32 elementwise, bitwise = ref) ----
    {
      const int urow = wr + tc;
      const int p = preds[urow];
      const float4* crow = (const float4*)(cbg + (size_t)p * DIM + 32 * hi);
      #pragma unroll
      for (int q = 0; q < 8; ++q) {
        const float4 cv = crow[q];
        float4* rp = (float4*)&res[urow][32 * hi + 4 * q];
        float4 rv = *rp;
        rv.x -= cv.x; rv.y -= cv.y; rv.z -= cv.z; rv.w -= cv.w;
        *rp = rv;
      }
    }
    __syncthreads();
  }

  // ---- z_q = z - residual_final ----
  {
    const float4* z4 = (const float4*)(z + (size_t)row0 * DIM);
    float4* o4 = (float4*)(zq + (size_t)row0 * DIM);
    #pragma unroll
    for (int i = 0; i < 8; ++i) {
      const int f = i * 256 + tid;
      float4 v = z4[f];
      const int r = (f * 4) >> 6, d0 = (f * 4) & 63;
      const float4 rv = *(const float4*)&res[r][d0];
      v.x -= rv.x; v.y -= rv.y; v.z -= rv.z; v.w -= rv.w;
      o4[f] = v;
    }
  }
}

extern "C" void kernel_launch(void* const* d_in, const int* in_sizes, int n_in,
                              void* d_out, int out_size, void* d_ws, size_t ws_size,
                              hipStream_t stream) {
  const float* z  = (const float*)d_in[0];
  const float* cb = (const float*)d_in[1];
  float* out = (float*)d_out;

  unsigned short* bh = (unsigned short*)d_ws;          // 65536 u16 = 128KB
  unsigned short* bl = bh + 65536;                     // 128KB
  float*          c2 = (float*)(bl + 65536);           // 4KB

  hipLaunchKernelGGL(prep_kernel, dim3(32), dim3(64), 0, stream, cb, bh, bl, c2);
  hipLaunchKernelGGL(rvq_mfma_kernel, dim3(B_TOTAL / BM), dim3(256), 0, stream,
                     z, cb, bh, bl, c2, out);
}

// Round 4
// 549.091 us; speedup vs baseline: 3.1716x; 1.7552x over previous
//
#include <hip/hip_runtime.h>
#include <cfloat>

#define B_TOTAL 131072
#define N_CB    1024
#define DIM     64
#define DEPTH   4
#define BM      128     // rows per block (4 waves x 32)
#define RS      68      // res row stride (floats): 272B, 16B-aligned rows, 4-bank stagger
#define EPS     0.075f  // band: covers bf16-split coarse err + 13-bit key truncation

typedef __bf16 bf16x8 __attribute__((ext_vector_type(8)));
typedef unsigned short u16x8 __attribute__((ext_vector_type(8)));
typedef float f32x16 __attribute__((ext_vector_type(16)));

#define MFMA(a, b, c) __builtin_amdgcn_mfma_f32_32x32x16_bf16(a, b, c, 0, 0, 0)

static __device__ __forceinline__ unsigned umin32(unsigned a, unsigned b) { return a < b ? a : b; }
static __device__ __forceinline__ unsigned umax32(unsigned a, unsigned b) { return a > b ? a : b; }

static __device__ __forceinline__ unsigned short f2bf(float f) {
  unsigned u = __builtin_bit_cast(unsigned, f);
  return (unsigned short)((u + 0x7fffu + ((u >> 16) & 1u)) >> 16);
}
static __device__ __forceinline__ float bf2f(unsigned short h) {
  unsigned u = ((unsigned)h) << 16;
  return __builtin_bit_cast(float, u);
}

// Pre-split codebook into MFMA B-fragment layout (bh/bl) + fp32 norms.
// frag element: [(t*4+m)*64 + lane][j] = cb[32t + (lane&31)][16m + 8*(lane>>5) + j]
__global__ void prep_kernel(const float* __restrict__ cb,
                            unsigned short* __restrict__ bh,
                            unsigned short* __restrict__ bl,
                            float* __restrict__ c2) {
  const int t = blockIdx.x;            // 0..31
  const int l = threadIdx.x;           // 0..63
  const int tc = l & 31, hi = l >> 5;
  const int row = 32 * t + tc;
  #pragma unroll
  for (int m = 0; m < 4; ++m) {
    const float* p = cb + row * DIM + 16 * m + 8 * hi;
    const size_t o = (((size_t)t * 4 + m) * 64 + l) * 8;
    #pragma unroll
    for (int j = 0; j < 8; ++j) {
      float f = p[j];
      unsigned short h = f2bf(f);
      bh[o + j] = h;
      bl[o + j] = f2bf(f - bf2f(h));
    }
  }
  if (hi == 0) {
    const float* p = cb + row * DIM;
    float s = 0.f;
    #pragma unroll
    for (int k = 0; k < DIM; ++k) s += p[k] * p[k];
    c2[row] = s;
  }
}

// LDS: res 34816 + c2s 4096 + z2s 512 + preds 512 = ~39.9KB -> 3 blocks/CU
__global__ __launch_bounds__(256, 3)
void rvq_mfma_kernel(const float* __restrict__ z,
                     const float* __restrict__ cbg,
                     const unsigned short* __restrict__ bh,
                     const unsigned short* __restrict__ bl,
                     const float* __restrict__ c2g,
                     float* __restrict__ out) {
  __shared__ __align__(16) float res[BM][RS];  // fp32 residual, per-wave 32-row panels
  __shared__ float c2s[N_CB];
  __shared__ float z2s[BM];
  __shared__ int   preds[BM];

  const int tid  = threadIdx.x;
  const int wave = tid >> 6;
  const int l    = tid & 63;
  const int tc   = l & 31;
  const int hi   = l >> 5;
  const int wr   = wave * 32;
  const int row0 = blockIdx.x * BM;

  float* zq   = out;
  float* maps = out + (size_t)B_TOTAL * DIM;

  // ---- stage z -> res (coalesced), c2 -> LDS ----
  {
    const float4* z4 = (const float4*)(z + (size_t)row0 * DIM);
    #pragma unroll
    for (int i = 0; i < 8; ++i) {
      const int f = i * 256 + tid;
      float4 v = z4[f];
      const int r = (f * 4) >> 6, d0 = (f * 4) & 63;
      *(float4*)&res[r][d0] = v;
    }
    for (int i = tid; i < N_CB; i += 256) c2s[i] = c2g[i];
  }
  __syncthreads();

  for (int depth = 0; depth < DEPTH; ++depth) {
    // ---- A fragments (split bf16) + fp32 row norm ----
    bf16x8 Ah[4], Al[4];
    float zp = 0.f;
    {
      const int arow = wr + tc;
      #pragma unroll
      for (int m = 0; m < 4; ++m) {
        u16x8 uh, ul;
        #pragma unroll
        for (int jj = 0; jj < 8; ++jj) {
          const float f = res[arow][16 * m + 8 * hi + jj];
          zp += f * f;
          const unsigned short h = f2bf(f);
          uh[jj] = h;
          ul[jj] = f2bf(f - bf2f(h));
        }
        Ah[m] = __builtin_bit_cast(bf16x8, uh);
        Al[m] = __builtin_bit_cast(bf16x8, ul);
      }
    }
    zp += __shfl_xor(zp, 32);          // partner lane holds the other 32 dims
    if (l < 32) z2s[wr + l] = zp;

    float z2v[16];
    #pragma unroll
    for (int s = 0; s < 16; ++s)
      z2v[s] = z2s[wr + (s & 3) + 8 * (s >> 2) + 4 * hi];

    // packed top-2 keys: (dist_bits & ~1023) | col ; uint order == (dist, col) order
    unsigned m1[16], m2[16];
    #pragma unroll
    for (int s = 0; s < 16; ++s) { m1[s] = 0xFFFFFFFFu; m2[s] = 0xFFFFFFFFu; }

    float* mbase = maps + ((size_t)depth * B_TOTAL + row0 + wr + 4 * hi) * N_CB + tc;

    for (int t = 0; t < 32; ++t) {
      const bf16x8* bhp = (const bf16x8*)bh + (size_t)(t * 4) * 64 + l;
      const bf16x8* blp = (const bf16x8*)bl + (size_t)(t * 4) * 64 + l;
      const bf16x8 Bh0 = bhp[0], Bh1 = bhp[64], Bh2 = bhp[128], Bh3 = bhp[192];
      const bf16x8 Bl0 = blp[0], Bl1 = blp[64], Bl2 = blp[128], Bl3 = blp[192];

      f32x16 acc;
      #pragma unroll
      for (int s = 0; s < 16; ++s) acc[s] = 0.f;
      acc = MFMA(Ah[0], Bh0, acc);
      acc = MFMA(Ah[1], Bh1, acc);
      acc = MFMA(Ah[2], Bh2, acc);
      acc = MFMA(Ah[3], Bh3, acc);
      acc = MFMA(Ah[0], Bl0, acc);
      acc = MFMA(Ah[1], Bl1, acc);
      acc = MFMA(Ah[2], Bl2, acc);
      acc = MFMA(Ah[3], Bl3, acc);
      acc = MFMA(Al[0], Bh0, acc);
      acc = MFMA(Al[1], Bh1, acc);
      acc = MFMA(Al[2], Bh2, acc);
      acc = MFMA(Al[3], Bh3, acc);

      const float c2v = c2s[32 * t + tc];
      const unsigned colp = (unsigned)(32 * t + tc);
      float* mp = mbase + 32 * t;
      #pragma unroll
      for (int s = 0; s < 16; ++s) {
        const float d = fmaf(-2.f, acc[s], z2v[s] + c2v);
        mp[((s & 3) + 8 * (s >> 2)) * N_CB] = d;   // 2x128B segments per wave store
        const float dc = fmaxf(d, 0.f);
        const unsigned k = (__builtin_bit_cast(unsigned, dc) & 0xFFFFFC00u) | colp;
        const unsigned t2 = umax32(m1[s], k);
        m1[s] = umin32(m1[s], k);
        m2[s] = umin32(m2[s], t2);
      }
    }

    // ---- decide pred per row; fp64 exact refine when band is ambiguous ----
    #pragma unroll
    for (int s = 0; s < 16; ++s) {
      const int row = wr + (s & 3) + 8 * (s >> 2) + 4 * hi;
      unsigned g1 = m1[s], g2 = m2[s];
      #pragma unroll
      for (int msk = 1; msk < 32; msk <<= 1) {
        const unsigned o1 = (unsigned)__shfl_xor((int)g1, msk);
        const unsigned o2 = (unsigned)__shfl_xor((int)g2, msk);
        const unsigned hi2 = umax32(g1, o1);
        g1 = umin32(g1, o1);
        g2 = umin32(umin32(g2, o2), hi2);
      }
      int pred = (int)(g1 & 1023u);
      const float d1f = __builtin_bit_cast(float, g1 & 0xFFFFFC00u);
      const float d2f = __builtin_bit_cast(float, g2 & 0xFFFFFC00u);
      if (d2f <= d1f + EPS) {
        const float thr = d1f + EPS;
        const bool c1 = __builtin_bit_cast(float, m1[s] & 0xFFFFFC00u) <= thr;
        const bool c2b = __builtin_bit_cast(float, m2[s] & 0xFFFFFC00u) <= thr;
        const unsigned long long B1 = __ballot(c1);
        const unsigned long long B2 = __ballot(c2b);
        const unsigned sh = tid & 32;
        unsigned b1 = (unsigned)(B1 >> sh);
        unsigned b2 = (unsigned)(B2 >> sh);
        const float2 rv = *(const float2*)&res[row][2 * tc];
        double best = DBL_MAX; int bix = 0x7fffffff;
        unsigned rem = b1;
        while (rem) {
          const int lb = __ffs(rem) - 1; rem &= rem - 1;
          const int cidx = __shfl((int)(m1[s] & 1023u), lb, 32);
          const float2 cv = *(const float2*)(cbg + (size_t)cidx * DIM + 2 * tc);
          double dp = ((double)rv.x - cv.x) * ((double)rv.x - cv.x)
                    + ((double)rv.y - cv.y) * ((double)rv.y - cv.y);
          #pragma unroll
          for (int msk = 1; msk < 32; msk <<= 1) dp += __shfl_xor(dp, msk);
          if (dp < best || (dp == best && cidx < bix)) { best = dp; bix = cidx; }
        }
        rem = b2;
        while (rem) {
          const int lb = __ffs(rem) - 1; rem &= rem - 1;
          const int cidx = __shfl((int)(m2[s] & 1023u), lb, 32);
          const float2 cv = *(const float2*)(cbg + (size_t)cidx * DIM + 2 * tc);
          double dp = ((double)rv.x - cv.x) * ((double)rv.x - cv.x)
                    + ((double)rv.y - cv.y) * ((double)rv.y - cv.y);
          #pragma unroll
          for (int msk = 1; msk < 32; msk <<= 1) dp += __shfl_xor(dp, msk);
          if (dp < best || (dp == best && cidx < bix)) { best = dp; bix = cidx; }
        }
        pred = bix;
      }
      if (tc == 0) preds[row] = pred;
    }

    // ---- residual -= codebook[pred] (fp32 elementwise, bitwise = ref) ----
    {
      const int urow = wr + tc;
      const int p = preds[urow];
      const float4* crow = (const float4*)(cbg + (size_t)p * DIM + 32 * hi);
      #pragma unroll
      for (int q = 0; q < 8; ++q) {
        const float4 cv = crow[q];
        float4* rp = (float4*)&res[urow][32 * hi + 4 * q];
        float4 rv = *rp;
        rv.x -= cv.x; rv.y -= cv.y; rv.z -= cv.z; rv.w -= cv.w;
        *rp = rv;
      }
    }
    __syncthreads();
  }

  // ---- z_q = z - residual_final ----
  {
    const float4* z4 = (const float4*)(z + (size_t)row0 * DIM);
    float4* o4 = (float4*)(zq + (size_t)row0 * DIM);
    #pragma unroll
    for (int i = 0; i < 8; ++i) {
      const int f = i * 256 + tid;
      float4 v = z4[f];
      const int r = (f * 4) >> 6, d0 = (f * 4) & 63;
      const float4 rv = *(const float4*)&res[r][d0];
      v.x -= rv.x; v.y -= rv.y; v.z -= rv.z; v.w -= rv.w;
      o4[f] = v;
    }
  }
}

extern "C" void kernel_launch(void* const* d_in, const int* in_sizes, int n_in,
                              void* d_out, int out_size, void* d_ws, size_t ws_size,
                              hipStream_t stream) {
  const float* z  = (const float*)d_in[0];
  const float* cb = (const float*)d_in[1];
  float* out = (float*)d_out;

  unsigned short* bh = (unsigned short*)d_ws;          // 65536 u16 = 128KB
  unsigned short* bl = bh + 65536;                     // 128KB
  float*          c2 = (float*)(bl + 65536);           // 4KB

  hipLaunchKernelGGL(prep_kernel, dim3(32), dim3(64), 0, stream, cb, bh, bl, c2);
  hipLaunchKernelGGL(rvq_mfma_kernel, dim3(B_TOTAL / BM), dim3(256), 0, stream,
                     z, cb, bh, bl, c2, out);
}